// Round 7
// baseline (627.026 us; speedup 1.0000x reference)
//
#include <hip/hip_runtime.h>
#include <math.h>

#define BB 4
#define SS 2048
#define DM 1024
#define NH 16

typedef unsigned short u16;
typedef __attribute__((ext_vector_type(8))) short bf16x8;
typedef __attribute__((ext_vector_type(4))) float f32x4;

__device__ __forceinline__ u16 f2bf(float f) {
  union { float f; unsigned u; } v; v.f = f;
  unsigned r = v.u + 0x7fffu + ((v.u >> 16) & 1u);
  return (u16)(r >> 16);
}
__device__ __forceinline__ float bf2f(u16 h) {
  union { unsigned u; float f; } v; v.u = ((unsigned)h) << 16;
  return v.f;
}
__device__ __forceinline__ void gl16(const u16* g, u16* l) {
  __builtin_amdgcn_global_load_lds((__attribute__((address_space(1))) void*)(u16*)g,
                                   (__attribute__((address_space(3))) void*)l, 16, 0, 0);
}

// barrier that waits only LDS ops (leaves global prefetch loads in flight).
#define BARRIER_LDS()                                    \
  do {                                                   \
    __builtin_amdgcn_sched_barrier(0);                   \
    asm volatile("s_waitcnt lgkmcnt(0)" ::: "memory");   \
    __builtin_amdgcn_s_barrier();                        \
    __builtin_amdgcn_sched_barrier(0);                   \
  } while (0)

// ---------------- fp32 -> bf16 conversion, 8 elems/thread ----------------
__global__ __launch_bounds__(256) void cvt_bf16(const float* __restrict__ in,
                                                u16* __restrict__ out, int n8) {
  int i = blockIdx.x * 256 + threadIdx.x;
  if (i >= n8) return;
  const float4* p = (const float4*)in + (size_t)i * 2;
  float4 a = p[0], b = p[1];
  ushort4 o0 = { f2bf(a.x), f2bf(a.y), f2bf(a.z), f2bf(a.w) };
  ushort4 o1 = { f2bf(b.x), f2bf(b.y), f2bf(b.z), f2bf(b.w) };
  ushort4* q = (ushort4*)out + (size_t)i * 2;
  q[0] = o0; q[1] = o1;
}

// ---------------- C[M,N] = A[M,K] @ W[N,K]^T + bias (bf16 MFMA) ----
// MODE 0: bf16 row-major C.  MODE 1: bf16 scatter to Vt[b,h,d,s].  MODE 2: fp32 C.
template <int MODE>
__global__ __launch_bounds__(256) void gemm_proj(const u16* __restrict__ A,
                                                 const u16* __restrict__ W,
                                                 const float* __restrict__ bias,
                                                 void* __restrict__ Cv,
                                                 int M, int N, int K) {
  __shared__ __align__(16) u16 As[128 * 32];
  __shared__ __align__(16) u16 Bs[128 * 32];
  const int t = threadIdx.x;
  const int w = t >> 6, l = t & 63;
  const int m0 = blockIdx.x * 128, n0 = blockIdx.y * 128;
  const int wm = (w >> 1) * 64, wn = (w & 1) * 64;
  const int lr = l & 15, lg = (l >> 4) * 8;
  const int sr = t >> 2, sc4 = (t & 3) * 8;

  const u16* Ap1 = A + (size_t)(m0 + sr) * K + sc4;
  const u16* Ap2 = Ap1 + (size_t)64 * K;
  const u16* Wp1 = W + (size_t)(n0 + sr) * K + sc4;
  const u16* Wp2 = Wp1 + (size_t)64 * K;
  u16* Asd1 = As + w * 512;
  u16* Asd2 = As + 2048 + w * 512;
  u16* Bsd1 = Bs + w * 512;
  u16* Bsd2 = Bs + 2048 + w * 512;

  f32x4 acc[4][4];
  f32x4 z4 = {0.f, 0.f, 0.f, 0.f};
#pragma unroll
  for (int i = 0; i < 4; ++i)
#pragma unroll
    for (int j = 0; j < 4; ++j) acc[i][j] = z4;

  for (int k0 = 0; k0 < K; k0 += 32) {
    __syncthreads();
    gl16(Ap1 + k0, Asd1);
    gl16(Ap2 + k0, Asd2);
    gl16(Wp1 + k0, Bsd1);
    gl16(Wp2 + k0, Bsd2);
    __syncthreads();
    bf16x8 af[4], bw[4];
#pragma unroll
    for (int i = 0; i < 4; ++i) {
      af[i] = *(const bf16x8*)&As[(wm + i * 16 + lr) * 32 + lg];
      bw[i] = *(const bf16x8*)&Bs[(wn + i * 16 + lr) * 32 + lg];
    }
#pragma unroll
    for (int i = 0; i < 4; ++i)
#pragma unroll
      for (int j = 0; j < 4; ++j)
        acc[i][j] = __builtin_amdgcn_mfma_f32_16x16x32_bf16(af[i], bw[j], acc[i][j], 0, 0, 0);
  }

  const int lg4 = (l >> 4) * 4;
#pragma unroll
  for (int j = 0; j < 4; ++j) {
    const int col = n0 + wn + j * 16 + lr;
    const float bj = bias[col];
#pragma unroll
    for (int i = 0; i < 4; ++i) {
#pragma unroll
      for (int r = 0; r < 4; ++r) {
        const int row = m0 + wm + i * 16 + lg4 + r;
        const float val = acc[i][j][r] + bj;
        if (MODE == 0) {
          ((u16*)Cv)[(size_t)row * N + col] = f2bf(val);
        } else if (MODE == 1) {
          ((u16*)Cv)[((size_t)((row >> 11) * 16 + (col >> 6)) * 64 + (col & 63)) * SS +
                     (row & 2047)] = f2bf(val);
        } else {
          ((float*)Cv)[(size_t)row * N + col] = val;
        }
      }
    }
  }
}

// -------- double softmax over 16 heads, lane-local fiber --------
// After pass 1, max_h exp(x-m) == 1.0 exactly, so pass 2 needs no max scan.
__device__ __forceinline__ void dsm16(float x[16]) {
  float m = x[0];
#pragma unroll
  for (int h = 1; h < 16; ++h) m = fmaxf(m, x[h]);
  float s = 0.f;
#pragma unroll
  for (int h = 0; h < 16; ++h) { x[h] = __expf(x[h] - m); s += x[h]; }
  const float inv = 0.125f / s;
  float s2 = 0.f;
#pragma unroll
  for (int h = 0; h < 16; ++h) { x[h] = __expf((x[h] - 1.0f) * inv); s2 += x[h]; }
  const float inv2 = 1.f / s2;
#pragma unroll
  for (int h = 0; h < 16; ++h) x[h] *= inv2;
}

// ===== fused attention: scores -> h-softmax^2 -> PV, per (b, 32q) =====
// 8 waves; wave w owns heads {2w,2w+1}. k-step 32, 64 steps.
// K and V read DIRECTLY global->VGPR (L2-resident; zero cross-wave reuse, so
// LDS staging was pure overhead). LDS holds only the Ws softmax-exchange
// buffer, double-buffered; 2 raw lgkmcnt-only barriers per step keep the
// K(t+1)/V(t+1) register prefetches in flight across barriers.
// Ws row stride 40 u16 (80 B, 16B-aligned) spreads spill/read banks.
#define WROW 40
#define WPLANE (32 * WROW)  // 1280 u16 per head-plane
__global__ __launch_bounds__(512, 2) void fused_attn(const u16* __restrict__ Qp,
                                                     const u16* __restrict__ Kp,
                                                     const u16* __restrict__ Vt,
                                                     u16* __restrict__ AO) {
  __shared__ __align__(16) u16 Ws[2][16 * WPLANE];  // 2 x 40 KB

  const int t = threadIdx.x;
  const int w = t >> 6, l = t & 63;
  const int lr = l & 15, lg = l >> 4;          // frag row (0..15), chunk (0..3)
  const int bid = blockIdx.x;
  const int xcd = bid & 7;                     // XCD-pinning: batch per XCD-pair
  const int b = xcd >> 1;
  const int qt = (xcd & 1) * 32 + (bid >> 3);  // 0..63
  const int q0 = qt * 32;
  const int h0 = w * 2;

  // hoisted Q fragments
  bf16x8 qf[2][2][2];
#pragma unroll
  for (int hh = 0; hh < 2; ++hh)
#pragma unroll
    for (int m = 0; m < 2; ++m)
#pragma unroll
      for (int dc = 0; dc < 2; ++dc)
        qf[hh][m][dc] = *(const bf16x8*)(Qp + ((size_t)b * SS + q0 + m * 16 + lr) * DM +
                                         (h0 + hh) * 64 + dc * 32 + lg * 8);

  // per-lane bases; static offsets folded per unrolled index
  const u16* kb = Kp + ((size_t)b * SS + lr) * DM + h0 * 64 + lg * 8;
  const u16* vb = Vt + (((size_t)b * 16 + h0) * 64 + lr) * SS + lg * 8;

  f32x4 o[2][2][4];
  f32x4 z4 = {0.f, 0.f, 0.f, 0.f};
#pragma unroll
  for (int hh = 0; hh < 2; ++hh)
#pragma unroll
    for (int m = 0; m < 2; ++m)
#pragma unroll
      for (int d = 0; d < 4; ++d) o[hh][m][d] = z4;

  const int sq = t >> 4;   // softmax fiber q (0..31)
  const int sk = t & 15;   // softmax fiber k-pair (0..15)

  bf16x8 kfr[8], vfr[8];   // kfr idx: hh*4+dc*2+n ; vfr idx: hh*4+ds
  // prologue: tile 0 fragments
#pragma unroll
  for (int hh = 0; hh < 2; ++hh)
#pragma unroll
    for (int dc = 0; dc < 2; ++dc)
#pragma unroll
      for (int n = 0; n < 2; ++n)
        kfr[hh * 4 + dc * 2 + n] =
            *(const bf16x8*)(kb + (size_t)(n * 16) * DM + hh * 64 + dc * 32);
#pragma unroll
  for (int hh = 0; hh < 2; ++hh)
#pragma unroll
    for (int ds = 0; ds < 4; ++ds)
      vfr[hh * 4 + ds] = *(const bf16x8*)(vb + (size_t)(hh * 64 + ds * 16) * SS);

  for (int tt = 0; tt < 64; ++tt) {
    u16* Wsb = &Ws[tt & 1][0];
    const size_t knext = (size_t)(((tt + 1) & 63) * 32) * DM;  // k-row advance
    const int vnext = ((tt + 1) & 63) * 32;                    // k-col advance

    // ---- P1: scores (swapped: lane holds 4 consecutive k for fixed q) ----
    f32x4 sa[2][2][2];
#pragma unroll
    for (int hh = 0; hh < 2; ++hh)
#pragma unroll
      for (int n = 0; n < 2; ++n)
#pragma unroll
        for (int m = 0; m < 2; ++m) sa[hh][n][m] = z4;
#pragma unroll
    for (int hh = 0; hh < 2; ++hh)
#pragma unroll
      for (int dc = 0; dc < 2; ++dc)
#pragma unroll
        for (int n = 0; n < 2; ++n)
#pragma unroll
          for (int m = 0; m < 2; ++m)
            sa[hh][n][m] = __builtin_amdgcn_mfma_f32_16x16x32_bf16(
                kfr[hh * 4 + dc * 2 + n], qf[hh][m][dc], sa[hh][n][m], 0, 0, 0);
    // spill scaled scores -> Ws[buf]
#pragma unroll
    for (int hh = 0; hh < 2; ++hh)
#pragma unroll
      for (int n = 0; n < 2; ++n)
#pragma unroll
        for (int m = 0; m < 2; ++m) {
          ushort4 pk = { f2bf(sa[hh][n][m][0] * 0.125f), f2bf(sa[hh][n][m][1] * 0.125f),
                         f2bf(sa[hh][n][m][2] * 0.125f), f2bf(sa[hh][n][m][3] * 0.125f) };
          *(ushort4*)&Wsb[(h0 + hh) * WPLANE + (m * 16 + lr) * WROW + n * 16 + lg * 4] = pk;
        }
    // prefetch K(t+1) -> kfr (in flight across the barriers below)
#pragma unroll
    for (int hh = 0; hh < 2; ++hh)
#pragma unroll
      for (int dc = 0; dc < 2; ++dc)
#pragma unroll
        for (int n = 0; n < 2; ++n)
          kfr[hh * 4 + dc * 2 + n] =
              *(const bf16x8*)(kb + knext + (size_t)(n * 16) * DM + hh * 64 + dc * 32);
    BARRIER_LDS();  // spill visible

    // ---- P2: double h-softmax, 2 fibers/thread ----
    {
      u16* fib = Wsb + sq * WROW + sk * 2;
      float xa[16], xb[16];
#pragma unroll
      for (int h = 0; h < 16; ++h) {
        const unsigned u = *(const unsigned*)(fib + h * WPLANE);
        xa[h] = bf2f((u16)(u & 0xffffu));
        xb[h] = bf2f((u16)(u >> 16));
      }
      dsm16(xa);
      dsm16(xb);
#pragma unroll
      for (int h = 0; h < 16; ++h)
        *(unsigned*)(fib + h * WPLANE) = (unsigned)f2bf(xa[h]) | ((unsigned)f2bf(xb[h]) << 16);
    }
    BARRIER_LDS();  // softmax visible

    // ---- P3: PV ----
#pragma unroll
    for (int hh = 0; hh < 2; ++hh) {
      bf16x8 aw[2];
#pragma unroll
      for (int m = 0; m < 2; ++m)
        aw[m] = *(const bf16x8*)&Wsb[(h0 + hh) * WPLANE + (m * 16 + lr) * WROW + lg * 8];
#pragma unroll
      for (int ds = 0; ds < 4; ++ds)
#pragma unroll
        for (int m = 0; m < 2; ++m)
          o[hh][m][ds] = __builtin_amdgcn_mfma_f32_16x16x32_bf16(aw[m], vfr[hh * 4 + ds],
                                                                 o[hh][m][ds], 0, 0, 0);
    }
    // prefetch V(t+1) (latency hidden under next scores+softmax)
#pragma unroll
    for (int hh = 0; hh < 2; ++hh)
#pragma unroll
      for (int ds = 0; ds < 4; ++ds)
        vfr[hh * 4 + ds] = *(const bf16x8*)(vb + vnext + (size_t)(hh * 64 + ds * 16) * SS);
    // no 3rd barrier: next spill targets the other Ws buffer
  }

  // ---- epilogue: AO[b, q0+row, h*64+d] ----
#pragma unroll
  for (int hh = 0; hh < 2; ++hh)
#pragma unroll
    for (int m = 0; m < 2; ++m)
#pragma unroll
      for (int ds = 0; ds < 4; ++ds)
#pragma unroll
        for (int r = 0; r < 4; ++r)
          AO[((size_t)b * SS + q0 + m * 16 + lg * 4 + r) * DM + (h0 + hh) * 64 + ds * 16 + lr] =
              f2bf(o[hh][m][ds][r]);
}

extern "C" void kernel_launch(void* const* d_in, const int* in_sizes, int n_in,
                              void* d_out, int out_size, void* d_ws, size_t ws_size,
                              hipStream_t stream) {
  const float* kin = (const float*)d_in[0];
  const float* qin = (const float*)d_in[1];
  const float* vin = (const float*)d_in[2];
  const float* Wq  = (const float*)d_in[3];
  const float* bq  = (const float*)d_in[4];
  const float* Wk  = (const float*)d_in[5];
  const float* bk  = (const float*)d_in[6];
  const float* Wv  = (const float*)d_in[7];
  const float* bv  = (const float*)d_in[8];
  const float* Wo  = (const float*)d_in[9];
  const float* bo  = (const float*)d_in[10];

  const size_t P   = (size_t)BB * SS * DM;   // 8388608
  const size_t WSZ = (size_t)DM * DM;
  u16* Qb  = (u16*)d_ws;
  u16* Kb  = Qb + P;
  u16* Vb  = Kb + P;
  u16* Wqb = Vb + P;
  u16* Wkb = Wqb + WSZ;
  u16* Wvb = Wkb + WSZ;
  u16* Wob = Wvb + WSZ;
  u16* Qp  = Wob + WSZ;
  u16* Kp  = Qp + P;
  u16* Vt  = Kp + P;     // [b,h,d,s]
  u16* AO  = Vt + P;

  cvt_bf16<<<dim3(4096), 256, 0, stream>>>(qin, Qb, (int)(P / 8));
  cvt_bf16<<<dim3(4096), 256, 0, stream>>>(kin, Kb, (int)(P / 8));
  cvt_bf16<<<dim3(4096), 256, 0, stream>>>(vin, Vb, (int)(P / 8));
  cvt_bf16<<<dim3(512), 256, 0, stream>>>(Wq, Wqb, (int)(WSZ / 8));
  cvt_bf16<<<dim3(512), 256, 0, stream>>>(Wk, Wkb, (int)(WSZ / 8));
  cvt_bf16<<<dim3(512), 256, 0, stream>>>(Wv, Wvb, (int)(WSZ / 8));
  cvt_bf16<<<dim3(512), 256, 0, stream>>>(Wo, Wob, (int)(WSZ / 8));

  dim3 gp(64, 8);
  gemm_proj<0><<<gp, 256, 0, stream>>>(Qb, Wqb, bq, Qp, 8192, 1024, 1024);
  gemm_proj<0><<<gp, 256, 0, stream>>>(Kb, Wkb, bk, Kp, 8192, 1024, 1024);
  gemm_proj<1><<<gp, 256, 0, stream>>>(Vb, Wvb, bv, Vt, 8192, 1024, 1024);

  fused_attn<<<dim3(256), 512, 0, stream>>>(Qp, Kp, Vt, AO);

  gemm_proj<2><<<gp, 256, 0, stream>>>(AO, Wob, bo, (float*)d_out, 8192, 1024, 1024);
}